// Round 6
// baseline (1353.886 us; speedup 1.0000x reference)
//
#include <hip/hip_runtime.h>

// RLIF forward, persistent kernel, stamp-in-word sync.
// Round 6 differential vs round 5 (PASS @1350us): consumer poll switched from
// atomicOr RMW (serializes at LLC per line: ~131K RMW/step/group over 64 lines)
// to relaxed agent-scope atomic LOADS (sc-coherent at LLC, no RMW serialization).
// Protocol unchanged: word = (t<<16)|16 spike bits, triple-buffered; stamp and
// payload share one dword so no cross-address ordering is required.

#define T_STEPS 256
#define BATCH   128
#define NNEUR   1024
#define DECAY_F 0.2f
#define THRESH  0.3f

typedef __attribute__((ext_vector_type(8))) short short8;
typedef __attribute__((ext_vector_type(4))) float f32x4;

union FU { short8 s; unsigned u[4]; };

__device__ __forceinline__ unsigned short f2bf_rn(float x) {
    unsigned u = __float_as_uint(x);
    return (unsigned short)((u + 0x7FFFu + ((u >> 16) & 1u)) >> 16);
}

__global__ void rlif_init(unsigned* __restrict__ ybits) {
    int i = blockIdx.x * 256 + threadIdx.x;
    if (i < 3 * BATCH * 64) ybits[i] = 0xFFFF0000u;   // stamp 0xFFFF: never matches t
}

__global__ __launch_bounds__(256, 1)
void rlif_persist(const float* __restrict__ tx,   // [T][B][N]
                  const float* __restrict__ Wr,   // [N][N]
                  const float* __restrict__ br,   // [N]
                  float* __restrict__ out,        // [T][B][N]
                  unsigned* __restrict__ ybits)   // [3][128][64] stamped words
{
    extern __shared__ char smem[];
    unsigned short* wlds = (unsigned short*)smem;        // 3 * [16][1024] bf16, swizzled
    float* red = (float*)(smem + 3 * 16 * 1024 * 2);     // [2][16][16] f32 k-reduce
    unsigned short* ys = (unsigned short*)(smem + 3 * 16 * 1024 * 2 + 2 * 16 * 16 * 4); // [32][66]

    const int tid = threadIdx.x;
    const int bb  = blockIdx.x >> 6;   // 0..3  batch-block (32 batches)
    const int ib  = blockIdx.x & 63;   // 0..63 neuron-block (16 neurons)
    const int i0  = ib * 16;
    const int b0  = bb * 32;
    const int w   = tid >> 6;          // wave 0..3
    const int l   = tid & 63;
    const int c   = l & 15;
    const int kg  = l >> 4;
    const int r   = w & 1;             // row-tile
    const int h   = w >> 1;            // k-half

    // ---- one-time: stage Wr rows [i0, i0+16) as exact 3-way bf16 split, swizzled ----
    for (int e = tid * 4; e < 16 * NNEUR; e += 256 * 4) {
        int row = e >> 10;
        int k   = e & 1023;
        float4 wv = *(const float4*)(Wr + (size_t)(i0 + row) * NNEUR + k);
        int ksw = k ^ ((row & 7) << 3);
        float wa[4] = {wv.x, wv.y, wv.z, wv.w};
        #pragma unroll
        for (int j = 0; j < 4; ++j) {
            float fw = wa[j];
            unsigned short hb = f2bf_rn(fw);
            float hf = __uint_as_float((unsigned)hb << 16);
            float rm = fw - hf;
            unsigned short mb = f2bf_rn(rm);
            float mf = __uint_as_float((unsigned)mb << 16);
            float rl = rm - mf;
            unsigned short lb = f2bf_rn(rl);
            wlds[0 * 16384 + row * 1024 + ksw + j] = hb;
            wlds[1 * 16384 + row * 1024 + ksw + j] = mb;
            wlds[2 * 16384 + row * 1024 + ksw + j] = lb;
        }
    }
    __syncthreads();

    const float brv = br[i0 + c];
    float vreg[4] = {0.f, 0.f, 0.f, 0.f};
    const size_t BN = (size_t)BATCH * NNEUR;

    for (int t = 0; t < T_STEPS; ++t) {
        float txv[4];
        if (w < 2) {
            #pragma unroll
            for (int j = 0; j < 4; ++j)
                txv[j] = tx[(size_t)t * BN + (size_t)(b0 + w * 16 + kg * 4 + j) * NNEUR + i0 + c];
        }

        // ---- stage spikes of step t-1 into LDS (poll stamped words via device-scope loads) ----
        if (t > 0) {
            unsigned* buf = ybits + (size_t)((t - 1) % 3) * (BATCH * 64);
            const unsigned want = (unsigned)(t - 1);
            unsigned pend = 0xFFu;    // 8 words per thread: wi = k*256 + tid
            for (;;) {
                #pragma unroll
                for (int k = 0; k < 8; ++k) {
                    if (pend & (1u << k)) {
                        int wi  = (k << 8) | tid;       // 0..2047
                        int row = wi >> 6;              // 0..31 (batch within block)
                        int col = wi & 63;              // writer wg column
                        unsigned v = __hip_atomic_load(&buf[(b0 + row) * 64 + col],
                                                       __ATOMIC_RELAXED, __HIP_MEMORY_SCOPE_AGENT);
                        if ((v >> 16) == want) {
                            ys[row * 66 + col] = (unsigned short)(v & 0xFFFFu);
                            pend &= ~(1u << k);
                        }
                    }
                }
                if (!pend) break;
                __builtin_amdgcn_s_sleep(1);
            }
        }
        __syncthreads();

        f32x4 acc = {0.f, 0.f, 0.f, 0.f};
        if (t > 0) {
            // A-frags: bf16 1.0 / 0.0 bit patterns (identical to round 2/5)
            short8 afr[16];
            #pragma unroll
            for (int ks = 0; ks < 16; ++ks) {
                unsigned wv = *(const unsigned*)(ys + (r * 16 + c) * 66 + 2 * (h * 16 + ks));
                unsigned byt = (wv >> (kg * 8)) & 0xFFu;
                FU f;
                #pragma unroll
                for (int q = 0; q < 4; ++q) {
                    f.u[q] = (((byt >> (2 * q)) & 1u) ? 0x00003F80u : 0u)
                           | (((byt >> (2 * q + 1)) & 1u) ? 0x3F800000u : 0u);
                }
                afr[ks] = f.s;
            }
            // single accumulator chain, mat-outer / ks-inner — proven exact order
            #pragma unroll
            for (int mat = 0; mat < 3; ++mat) {
                #pragma unroll
                for (int ks = 0; ks < 16; ++ks) {
                    int kel = h * 512 + ks * 32 + kg * 8;
                    int sw  = kel ^ ((c & 7) << 3);
                    short8 bfr = *(const short8*)(wlds + mat * 16384 + c * 1024 + sw);
                    acc = __builtin_amdgcn_mfma_f32_16x16x32_bf16(afr[ks], bfr, acc, 0, 0, 0);
                }
            }
        }

        if (w >= 2) {
            #pragma unroll
            for (int j = 0; j < 4; ++j)
                red[r * 256 + (kg * 4 + j) * 16 + c] = acc[j];
        }
        __syncthreads();

        if (w < 2) {
            float* op = out + (size_t)t * BN;
            unsigned* pbuf = ybits + (size_t)(t % 3) * (BATCH * 64);
            #pragma unroll
            for (int j = 0; j < 4; ++j) {
                float z  = acc[j] + red[w * 256 + (kg * 4 + j) * 16 + c];
                float x  = (txv[j] + z) + brv;
                float vv = DECAY_F * vreg[j] + x;
                int   sp = vv > THRESH;
                vreg[j]  = sp ? 0.f : vv;
                op[(size_t)(b0 + w * 16 + kg * 4 + j) * NNEUR + i0 + c] = sp ? 1.f : 0.f;
                unsigned long long m = __ballot(sp != 0);
                if (c == j) {
                    unsigned u16v = (unsigned)((m >> (kg * 16)) & 0xFFFFu);
                    atomicExch(&pbuf[(b0 + w * 16 + kg * 4 + j) * 64 + ib],
                               ((unsigned)t << 16) | u16v);
                }
            }
        }
        // no end-of-step barrier: stamp polling is the synchronization
    }
}

extern "C" void kernel_launch(void* const* d_in, const int* in_sizes, int n_in,
                              void* d_out, int out_size, void* d_ws, size_t ws_size,
                              hipStream_t stream)
{
    const float* tx = (const float*)d_in[0];
    const float* Wr = (const float*)d_in[1];
    const float* br = (const float*)d_in[2];
    float* out = (float*)d_out;
    unsigned* ybits = (unsigned*)d_ws;   // [3][128][64] u32 = 96 KB

    const int lds_bytes = 3 * 16 * 1024 * 2 + 2 * 16 * 16 * 4 + 32 * 66 * 2;  // 103552
    hipFuncSetAttribute(reinterpret_cast<const void*>(rlif_persist),
                        hipFuncAttributeMaxDynamicSharedMemorySize, lds_bytes);

    rlif_init<<<dim3(96), dim3(256), 0, stream>>>(ybits);
    rlif_persist<<<dim3(256), dim3(256), lds_bytes, stream>>>(tx, Wr, br, out, ybits);
}